// Round 18
// baseline (422.329 us; speedup 1.0000x reference)
//
#include <hip/hip_runtime.h>
#include <math.h>

#define N_NODES 20000
#define NUM_EDGE 4096
#define DIM 256
#define KF 8
#define EOUT (KF + NUM_EDGE)   /* 4104 */
#define SEL 6001               /* floor(0.3*N)=6000 -> rank<=6000 -> 6001 nodes selected */

__device__ __forceinline__ unsigned fkey(float s) {
    unsigned u = __float_as_uint(s);
    return (u & 0x80000000u) ? ~u : (u | 0x80000000u);
}

__device__ __forceinline__ double wred(double v) {
#pragma unroll
    for (int m = 32; m > 0; m >>= 1) v += __shfl_xor(v, m);
    return v;
}
__device__ __forceinline__ float wredf(float v) {
#pragma unroll
    for (int m = 32; m > 0; m >>= 1) v += __shfl_xor(v, m);
    return v;
}

// K1e: en (per-block in LDS) + keys, interleaved butterflies (validated round 15).
__global__ __launch_bounds__(256) void k1e(const float* __restrict__ hidden,
                                           const float* __restrict__ int_emb,
                                           unsigned* __restrict__ keys) {
    __shared__ float en_s[KF * DIM];
    int tid = threadIdx.x, lane = tid & 63, w = tid >> 6;
    for (int f = w; f < KF; f += 4) {
        float4 e = ((const float4*)(int_emb + f * DIM))[lane];
        double ss = (double)e.x * e.x + (double)e.y * e.y + (double)e.z * e.z + (double)e.w * e.w;
        ss = wred(ss);
        float den = fmaxf((float)sqrt(ss), 1e-8f);
        float4 o;
        o.x = e.x / den; o.y = e.y / den; o.z = e.z / den; o.w = e.w / den;
        ((float4*)(en_s + f * DIM))[lane] = o;
    }
    __syncthreads();
    int n = blockIdx.x * 4 + w;
    if (n >= N_NODES) return;
    float4 h = ((const float4*)(hidden + (size_t)n * DIM))[lane];
    double ss = (double)h.x * h.x + (double)h.y * h.y + (double)h.z * h.z + (double)h.w * h.w;
    ss = wred(ss);
    float den = fmaxf((float)sqrt(ss), 1e-8f);
    float hn0 = h.x / den, hn1 = h.y / den, hn2 = h.z / den, hn3 = h.w / den;
    double d[KF];
#pragma unroll
    for (int f = 0; f < KF; ++f) {
        float4 e = ((const float4*)(en_s + f * DIM))[lane];
        d[f] = (double)hn0 * e.x + (double)hn1 * e.y + (double)hn2 * e.z + (double)hn3 * e.w;
    }
#pragma unroll
    for (int st = 32; st > 0; st >>= 1) {
#pragma unroll
        for (int f = 0; f < KF; ++f) d[f] += __shfl_xor(d[f], st);
    }
    if (lane < KF)
        keys[(size_t)lane * N_NODES + n] = fkey((float)(10.0 * d[lane]));
}

// K2: per factor: radix-select threshold key T, #ties needed, sorted tie list. (validated)
__global__ __launch_bounds__(1024) void k2_select(const unsigned* __restrict__ keys,
                                                  unsigned* __restrict__ T, int* __restrict__ need,
                                                  int* __restrict__ eqn, int* __restrict__ eqlist) {
    int f = blockIdx.x, tid = threadIdx.x;
    const unsigned* col = keys + (size_t)f * N_NODES;
    __shared__ unsigned hist[256];
    __shared__ int s_neq;
    unsigned prefix = 0u, pmask = 0u;
    int k = SEL;
    for (int shift = 24; shift >= 0; shift -= 8) {
        if (tid < 256) hist[tid] = 0u;
        __syncthreads();
        for (int i = tid; i < N_NODES; i += 1024) {
            unsigned key = col[i];
            if ((key & pmask) == prefix) atomicAdd(&hist[(key >> shift) & 255u], 1u);
        }
        __syncthreads();
        int acc = 0; unsigned chosen = 0u;   // identical scan in every thread
        for (int b = 255; b >= 0; --b) {
            int c = (int)hist[b];
            if (acc + c >= k) { chosen = (unsigned)b; k -= acc; break; }
            acc += c;
        }
        prefix |= chosen << shift;
        pmask |= 255u << shift;
        __syncthreads();
    }
    if (tid == 0) { T[f] = prefix; need[f] = k; s_neq = 0; }
    __syncthreads();
    for (int i = tid; i < N_NODES; i += 1024) {
        if (col[i] == prefix) {
            int p = atomicAdd(&s_neq, 1);
            if (p < 64) eqlist[f * 64 + p] = i;
        }
    }
    __syncthreads();
    if (tid == 0) {
        int ne = s_neq < 64 ? s_neq : 64;
        for (int a = 1; a < ne; ++a) {
            int v = eqlist[f * 64 + a]; int b = a - 1;
            while (b >= 0 && eqlist[f * 64 + b] > v) { eqlist[f * 64 + b + 1] = eqlist[f * 64 + b]; --b; }
            eqlist[f * 64 + b + 1] = v;
        }
        eqn[f] = ne;
    }
}

// K2.5: per-node selection mask; zeroes the int_H accumulator slots. (validated)
__global__ __launch_bounds__(256) void k25_mask(const unsigned* __restrict__ keys,
                                                const unsigned* __restrict__ T, const int* __restrict__ need,
                                                const int* __restrict__ eqn, const int* __restrict__ eqlist,
                                                unsigned* __restrict__ mask32, unsigned* __restrict__ accum32) {
    int g = blockIdx.x * 256 + threadIdx.x;
    if (g < 16) accum32[g] = 0u;          // accum64[0..7] (int_H) — only slots still atomic
    if (g >= N_NODES) return;
    unsigned m = 0u;
#pragma unroll
    for (int f = 0; f < KF; ++f) {
        unsigned key = keys[(size_t)f * N_NODES + g];
        unsigned t = T[f];
        bool sel = key > t;
        if (key == t) {
            int ne = eqn[f], nd = need[f], pos = -1;
            for (int i = 0; i < ne; ++i) if (eqlist[f * 64 + i] == g) { pos = i; break; }
            sel = (pos >= 0 && pos < nd);
        }
        m |= (sel ? 1u : 0u) << f;
    }
    mask32[g] = m;
}

// kAB: validated fused stream, partial-store tail, templated rows/wave for
//      block-count scaling (wave-starvation A/B). acc[64] keeps VGPR~110.
template<int RPWT>
__global__ __launch_bounds__(256) void kAB(const float* __restrict__ H,
                                           const unsigned* __restrict__ mask32,
                                           float* __restrict__ out,
                                           unsigned long long* __restrict__ accum64,
                                           unsigned* __restrict__ partial) {
    __shared__ unsigned lacc[NUM_EDGE];
    __shared__ unsigned s_int[KF];
    int tid = threadIdx.x, lane = tid & 63, w = tid >> 6;
    for (int i = tid; i < NUM_EDGE; i += 256) lacc[i] = 0u;
    if (tid < KF) s_int[tid] = 0u;
    __syncthreads();
    unsigned acc[64];
#pragma unroll
    for (int i = 0; i < 64; ++i) acc[i] = 0u;
    int n0 = (blockIdx.x * 4 + w) * RPWT;
    for (int r = 0; r < RPWT; ++r) {
        int n = n0 + r;
        const float4* hrow = (const float4*)(H + (size_t)n * NUM_EDGE);
        float4* orow = (float4*)(out + (size_t)n * EOUT + KF);
        float4 v[16];
#pragma unroll
        for (int c = 0; c < 16; ++c) v[c] = hrow[c * 64 + lane];
        float rsum = 0.f;
#pragma unroll
        for (int c = 0; c < 16; ++c) {
            orow[c * 64 + lane] = v[c];
            rsum += (v[c].x + v[c].y) + (v[c].z + v[c].w);
        }
        rsum = wredf(rsum);
        unsigned m = mask32[n];
        float degraw = rsum + 2.f * (float)__popc(m & 255u);   // exact small integer
        unsigned packed = (unsigned)degraw + (1u << 24);
        if (lane < KF) {
            unsigned sel = (m >> lane) & 1u;
            out[(size_t)n * EOUT + lane] = sel ? 2.0f : 0.0f;
            if (sel) atomicAdd(&s_int[lane], packed);
        }
        if (lane == 0)
            out[(size_t)N_NODES * EOUT + n] =
                (degraw > 0.f) ? (float)(1.0 / sqrt((double)degraw)) : 1.0f;
#pragma unroll
        for (int c = 0; c < 16; ++c) {
            if (v[c].x != 0.f) acc[c * 4 + 0] += packed;
            if (v[c].y != 0.f) acc[c * 4 + 1] += packed;
            if (v[c].z != 0.f) acc[c * 4 + 2] += packed;
            if (v[c].w != 0.f) acc[c * 4 + 3] += packed;
        }
    }
    // wave -> LDS (conflict-free: consecutive lanes -> consecutive banks).
#pragma unroll
    for (int cj = 0; cj < 64; ++cj)
        atomicAdd(&lacc[cj * 64 + lane], acc[cj]);
    __syncthreads();
    // LDS -> per-block partial buffer, plain coalesced stores (no global atomics).
    for (int i = tid; i < NUM_EDGE; i += 256)
        partial[(size_t)blockIdx.x * NUM_EDGE + i] = lacc[i];
    if (tid < KF) {
        unsigned p = s_int[tid];
        if (p) atomicAdd(&accum64[tid],
                         (unsigned long long)(p & 0xFFFFFFu) |
                         ((unsigned long long)(p >> 24) << 32));
    }
}

// kRd: reduce per-block partials and write degE directly (kR+k4 fused).
//      Block 0 additionally handles the KF int_H columns from accum64[0..7].
__global__ __launch_bounds__(256) void kRd(const unsigned* __restrict__ partial, int nblk,
                                           const unsigned long long* __restrict__ accum64,
                                           float* __restrict__ out) {
    int i = blockIdx.x * 256 + threadIdx.x;   // 16 blocks x 256 = 4096
    unsigned lo = 0u, hi = 0u;
    for (int b = 0; b < nblk; ++b) {
        unsigned p = partial[(size_t)b * NUM_EDGE + i];
        lo += p & 0xFFFFFFu;
        hi += p >> 24;
    }
    int lane_i = i & 63, cj = i >> 6, c = cj >> 2, j = cj & 3;
    int col = (c * 64 + lane_i) * 4 + j;
    double mean = (double)lo / (double)(hi ? hi : 1u);
    out[(size_t)N_NODES * EOUT + N_NODES + KF + col] = (float)(1.0 / sqrt(mean));
    if (blockIdx.x == 0 && threadIdx.x < KF) {
        unsigned long long a = accum64[threadIdx.x];
        unsigned s = (unsigned)a, cnt = (unsigned)(a >> 32);
        double mn = (double)s / (double)(cnt ? cnt : 1u);
        out[(size_t)N_NODES * EOUT + N_NODES + threadIdx.x] = (float)(1.0 / sqrt(mn));
    }
}

extern "C" void kernel_launch(void* const* d_in, const int* in_sizes, int n_in,
                              void* d_out, int out_size, void* d_ws, size_t ws_size,
                              hipStream_t stream) {
    const float* hidden  = (const float*)d_in[0];
    const float* H       = (const float*)d_in[1];
    const float* int_emb = (const float*)d_in[2];
    float* out = (float*)d_out;
    char* ws = (char*)d_ws;

    // ws layout (bytes):
    //   keys    0      (640000)
    //   T       640000 (32) | need 640032 (32) | eqn 640064 (32) | eqlist 640096 (2048)
    //   accum64 642144 (32832, 8-aligned)
    //   mask32  674976 (80000)
    //   partial 754976 (625 blocks: 10,240,000 — proven in round 14; 1000 blocks: 16,384,000)
    unsigned*           keys    = (unsigned*)ws;
    unsigned*           T       = (unsigned*)(ws + 640000);
    int*                need    = (int*)(ws + 640032);
    int*                eqn     = (int*)(ws + 640064);
    int*                eqlist  = (int*)(ws + 640096);
    unsigned long long* accum64 = (unsigned long long*)(ws + 642144);
    unsigned*           mask32  = (unsigned*)(ws + 674976);
    unsigned*           partial = (unsigned*)(ws + 754976);

    bool big = ws_size >= (size_t)754976 + 16384000ull;
    int nblk = big ? 1000 : 625;

    hipLaunchKernelGGL(k1e,       dim3(5000), dim3(256),  0, stream, hidden, int_emb, keys);
    hipLaunchKernelGGL(k2_select, dim3(8),    dim3(1024), 0, stream, keys, T, need, eqn, eqlist);
    hipLaunchKernelGGL(k25_mask,  dim3(80),   dim3(256),  0, stream, keys, T, need, eqn, eqlist,
                       mask32, (unsigned*)accum64);
    if (big) {
        hipLaunchKernelGGL((kAB<5>), dim3(1000), dim3(256), 0, stream, H, mask32, out, accum64, partial);
    } else {
        hipLaunchKernelGGL((kAB<8>), dim3(625),  dim3(256), 0, stream, H, mask32, out, accum64, partial);
    }
    hipLaunchKernelGGL(kRd,       dim3(16),   dim3(256),  0, stream, partial, nblk, accum64, out);
}

// Round 19
// 249.236 us; speedup vs baseline: 1.6945x; 1.6945x over previous
//
#include <hip/hip_runtime.h>
#include <math.h>

#define N_NODES 20000
#define NUM_EDGE 4096
#define DIM 256
#define KF 8
#define EOUT (KF + NUM_EDGE)   /* 4104 */
#define SEL 6001               /* floor(0.3*N)=6000 -> rank<=6000 -> 6001 nodes selected */

__device__ __forceinline__ unsigned fkey(float s) {
    unsigned u = __float_as_uint(s);
    return (u & 0x80000000u) ? ~u : (u | 0x80000000u);
}

__device__ __forceinline__ double wred(double v) {
#pragma unroll
    for (int m = 32; m > 0; m >>= 1) v += __shfl_xor(v, m);
    return v;
}
__device__ __forceinline__ float wredf(float v) {
#pragma unroll
    for (int m = 32; m > 0; m >>= 1) v += __shfl_xor(v, m);
    return v;
}

// K1e: en (per-block in LDS) + keys, interleaved butterflies (validated round 15).
__global__ __launch_bounds__(256) void k1e(const float* __restrict__ hidden,
                                           const float* __restrict__ int_emb,
                                           unsigned* __restrict__ keys) {
    __shared__ float en_s[KF * DIM];
    int tid = threadIdx.x, lane = tid & 63, w = tid >> 6;
    for (int f = w; f < KF; f += 4) {
        float4 e = ((const float4*)(int_emb + f * DIM))[lane];
        double ss = (double)e.x * e.x + (double)e.y * e.y + (double)e.z * e.z + (double)e.w * e.w;
        ss = wred(ss);
        float den = fmaxf((float)sqrt(ss), 1e-8f);
        float4 o;
        o.x = e.x / den; o.y = e.y / den; o.z = e.z / den; o.w = e.w / den;
        ((float4*)(en_s + f * DIM))[lane] = o;
    }
    __syncthreads();
    int n = blockIdx.x * 4 + w;
    if (n >= N_NODES) return;
    float4 h = ((const float4*)(hidden + (size_t)n * DIM))[lane];
    double ss = (double)h.x * h.x + (double)h.y * h.y + (double)h.z * h.z + (double)h.w * h.w;
    ss = wred(ss);
    float den = fmaxf((float)sqrt(ss), 1e-8f);
    float hn0 = h.x / den, hn1 = h.y / den, hn2 = h.z / den, hn3 = h.w / den;
    double d[KF];
#pragma unroll
    for (int f = 0; f < KF; ++f) {
        float4 e = ((const float4*)(en_s + f * DIM))[lane];
        d[f] = (double)hn0 * e.x + (double)hn1 * e.y + (double)hn2 * e.z + (double)hn3 * e.w;
    }
#pragma unroll
    for (int st = 32; st > 0; st >>= 1) {
#pragma unroll
        for (int f = 0; f < KF; ++f) d[f] += __shfl_xor(d[f], st);
    }
    if (lane < KF)
        keys[(size_t)lane * N_NODES + n] = fkey((float)(10.0 * d[lane]));
}

// K2: per factor: radix-select threshold key T, #ties needed, sorted tie list. (validated)
__global__ __launch_bounds__(1024) void k2_select(const unsigned* __restrict__ keys,
                                                  unsigned* __restrict__ T, int* __restrict__ need,
                                                  int* __restrict__ eqn, int* __restrict__ eqlist) {
    int f = blockIdx.x, tid = threadIdx.x;
    const unsigned* col = keys + (size_t)f * N_NODES;
    __shared__ unsigned hist[256];
    __shared__ int s_neq;
    unsigned prefix = 0u, pmask = 0u;
    int k = SEL;
    for (int shift = 24; shift >= 0; shift -= 8) {
        if (tid < 256) hist[tid] = 0u;
        __syncthreads();
        for (int i = tid; i < N_NODES; i += 1024) {
            unsigned key = col[i];
            if ((key & pmask) == prefix) atomicAdd(&hist[(key >> shift) & 255u], 1u);
        }
        __syncthreads();
        int acc = 0; unsigned chosen = 0u;   // identical scan in every thread
        for (int b = 255; b >= 0; --b) {
            int c = (int)hist[b];
            if (acc + c >= k) { chosen = (unsigned)b; k -= acc; break; }
            acc += c;
        }
        prefix |= chosen << shift;
        pmask |= 255u << shift;
        __syncthreads();
    }
    if (tid == 0) { T[f] = prefix; need[f] = k; s_neq = 0; }
    __syncthreads();
    for (int i = tid; i < N_NODES; i += 1024) {
        if (col[i] == prefix) {
            int p = atomicAdd(&s_neq, 1);
            if (p < 64) eqlist[f * 64 + p] = i;
        }
    }
    __syncthreads();
    if (tid == 0) {
        int ne = s_neq < 64 ? s_neq : 64;
        for (int a = 1; a < ne; ++a) {
            int v = eqlist[f * 64 + a]; int b = a - 1;
            while (b >= 0 && eqlist[f * 64 + b] > v) { eqlist[f * 64 + b + 1] = eqlist[f * 64 + b]; --b; }
            eqlist[f * 64 + b + 1] = v;
        }
        eqn[f] = ne;
    }
}

// K2.5: per-node selection mask; zeroes the full accum64 region (as u32 lanes). (validated)
__global__ __launch_bounds__(256) void k25_mask(const unsigned* __restrict__ keys,
                                                const unsigned* __restrict__ T, const int* __restrict__ need,
                                                const int* __restrict__ eqn, const int* __restrict__ eqlist,
                                                unsigned* __restrict__ mask32, unsigned* __restrict__ accum32) {
    int g = blockIdx.x * 256 + threadIdx.x;
    if (g < 2 * EOUT) accum32[g] = 0u;
    if (g >= N_NODES) return;
    unsigned m = 0u;
#pragma unroll
    for (int f = 0; f < KF; ++f) {
        unsigned key = keys[(size_t)f * N_NODES + g];
        unsigned t = T[f];
        bool sel = key > t;
        if (key == t) {
            int ne = eqn[f], nd = need[f], pos = -1;
            for (int i = 0; i < ne; ++i) if (eqlist[f * 64 + i] == g) { pos = i; break; }
            sel = (pos >= 0 && pos < nd);
        }
        m |= (sel ? 1u : 0u) << f;
    }
    mask32[g] = m;
}

// kAB: validated fused stream, partial-store tail, templated rows/wave. acc[64] keeps VGPR~110.
template<int RPWT>
__global__ __launch_bounds__(256) void kAB(const float* __restrict__ H,
                                           const unsigned* __restrict__ mask32,
                                           float* __restrict__ out,
                                           unsigned long long* __restrict__ accum64,
                                           unsigned* __restrict__ partial) {
    __shared__ unsigned lacc[NUM_EDGE];
    __shared__ unsigned s_int[KF];
    int tid = threadIdx.x, lane = tid & 63, w = tid >> 6;
    for (int i = tid; i < NUM_EDGE; i += 256) lacc[i] = 0u;
    if (tid < KF) s_int[tid] = 0u;
    __syncthreads();
    unsigned acc[64];
#pragma unroll
    for (int i = 0; i < 64; ++i) acc[i] = 0u;
    int n0 = (blockIdx.x * 4 + w) * RPWT;
    for (int r = 0; r < RPWT; ++r) {
        int n = n0 + r;
        const float4* hrow = (const float4*)(H + (size_t)n * NUM_EDGE);
        float4* orow = (float4*)(out + (size_t)n * EOUT + KF);
        float4 v[16];
#pragma unroll
        for (int c = 0; c < 16; ++c) v[c] = hrow[c * 64 + lane];
        float rsum = 0.f;
#pragma unroll
        for (int c = 0; c < 16; ++c) {
            orow[c * 64 + lane] = v[c];
            rsum += (v[c].x + v[c].y) + (v[c].z + v[c].w);
        }
        rsum = wredf(rsum);
        unsigned m = mask32[n];
        float degraw = rsum + 2.f * (float)__popc(m & 255u);   // exact small integer
        unsigned packed = (unsigned)degraw + (1u << 24);
        if (lane < KF) {
            unsigned sel = (m >> lane) & 1u;
            out[(size_t)n * EOUT + lane] = sel ? 2.0f : 0.0f;
            if (sel) atomicAdd(&s_int[lane], packed);
        }
        if (lane == 0)
            out[(size_t)N_NODES * EOUT + n] =
                (degraw > 0.f) ? (float)(1.0 / sqrt((double)degraw)) : 1.0f;
#pragma unroll
        for (int c = 0; c < 16; ++c) {
            if (v[c].x != 0.f) acc[c * 4 + 0] += packed;
            if (v[c].y != 0.f) acc[c * 4 + 1] += packed;
            if (v[c].z != 0.f) acc[c * 4 + 2] += packed;
            if (v[c].w != 0.f) acc[c * 4 + 3] += packed;
        }
    }
    // wave -> LDS (conflict-free: consecutive lanes -> consecutive banks).
#pragma unroll
    for (int cj = 0; cj < 64; ++cj)
        atomicAdd(&lacc[cj * 64 + lane], acc[cj]);
    __syncthreads();
    // LDS -> per-block partial buffer, plain coalesced stores (no global atomics).
    for (int i = tid; i < NUM_EDGE; i += 256)
        partial[(size_t)blockIdx.x * NUM_EDGE + i] = lacc[i];
    if (tid < KF) {
        unsigned p = s_int[tid];
        if (p) atomicAdd(&accum64[tid],
                         (unsigned long long)(p & 0xFFFFFFu) |
                         ((unsigned long long)(p >> 24) << 32));
    }
}

// kRd2: parallel partial reduction. 256 blocks = 16 column-chunks x 16 b-chunks;
//       each thread sums ~nblk/16 partials for ONE column, then a single u64 atomic.
//       (lo-field global sums < 2^32 -> no carry between packed fields; exact.)
__global__ __launch_bounds__(256) void kRd2(const unsigned* __restrict__ partial, int nblk,
                                            unsigned long long* __restrict__ accum64) {
    int ic = blockIdx.x & 15, bc = blockIdx.x >> 4;
    int i = ic * 256 + threadIdx.x;                  // lacc index (column-coded)
    int chunk = (nblk + 15) / 16;
    int b0 = bc * chunk, b1 = min(nblk, b0 + chunk);
    unsigned lo = 0u, hi = 0u;
    for (int b = b0; b < b1; ++b) {
        unsigned p = partial[(size_t)b * NUM_EDGE + i];
        lo += p & 0xFFFFFFu;
        hi += p >> 24;
    }
    int lane_i = i & 63, cj = i >> 6, c = cj >> 2, j = cj & 3;
    int col = (c * 64 + lane_i) * 4 + j;
    if (lo | hi)
        atomicAdd(&accum64[KF + col],
                  (unsigned long long)lo | ((unsigned long long)hi << 32));
}

// K4: degE[j] = (sum/max(cnt,1))^-0.5 from packed u64.
__global__ __launch_bounds__(256) void k4_dege(const unsigned long long* __restrict__ accum64,
                                               float* __restrict__ out) {
    int j = blockIdx.x * 256 + threadIdx.x;
    if (j >= EOUT) return;
    unsigned long long a = accum64[j];
    unsigned s = (unsigned)a, c = (unsigned)(a >> 32);
    double mean = (double)s / (double)(c ? c : 1u);
    out[(size_t)N_NODES * EOUT + N_NODES + j] = (float)(1.0 / sqrt(mean));
}

extern "C" void kernel_launch(void* const* d_in, const int* in_sizes, int n_in,
                              void* d_out, int out_size, void* d_ws, size_t ws_size,
                              hipStream_t stream) {
    const float* hidden  = (const float*)d_in[0];
    const float* H       = (const float*)d_in[1];
    const float* int_emb = (const float*)d_in[2];
    float* out = (float*)d_out;
    char* ws = (char*)d_ws;

    // ws layout (bytes):
    //   keys    0      (640000)
    //   T       640000 (32) | need 640032 (32) | eqn 640064 (32) | eqlist 640096 (2048)
    //   accum64 642144 (32832, 8-aligned)
    //   mask32  674976 (80000)
    //   partial 754976 (625 blocks: 10,240,000 — proven; 1000 blocks: 16,384,000)
    unsigned*           keys    = (unsigned*)ws;
    unsigned*           T       = (unsigned*)(ws + 640000);
    int*                need    = (int*)(ws + 640032);
    int*                eqn     = (int*)(ws + 640064);
    int*                eqlist  = (int*)(ws + 640096);
    unsigned long long* accum64 = (unsigned long long*)(ws + 642144);
    unsigned*           mask32  = (unsigned*)(ws + 674976);
    unsigned*           partial = (unsigned*)(ws + 754976);

    bool big = ws_size >= (size_t)754976 + 16384000ull;
    int nblk = big ? 1000 : 625;

    hipLaunchKernelGGL(k1e,       dim3(5000), dim3(256),  0, stream, hidden, int_emb, keys);
    hipLaunchKernelGGL(k2_select, dim3(8),    dim3(1024), 0, stream, keys, T, need, eqn, eqlist);
    hipLaunchKernelGGL(k25_mask,  dim3(80),   dim3(256),  0, stream, keys, T, need, eqn, eqlist,
                       mask32, (unsigned*)accum64);
    if (big) {
        hipLaunchKernelGGL((kAB<5>), dim3(1000), dim3(256), 0, stream, H, mask32, out, accum64, partial);
    } else {
        hipLaunchKernelGGL((kAB<8>), dim3(625),  dim3(256), 0, stream, H, mask32, out, accum64, partial);
    }
    hipLaunchKernelGGL(kRd2,      dim3(256),  dim3(256),  0, stream, partial, nblk, accum64);
    hipLaunchKernelGGL(k4_dege,   dim3(17),   dim3(256),  0, stream, accum64, out);
}